// Round 2
// baseline (11.284 us; speedup 1.0000x reference)
//
#include <hip/hip_runtime.h>

#define DT_F 0.01f
#define BUFLEN 102

// searchsorted(side='left') + clip(1,7) + lerp, matching _interp_lut exactly.
__device__ __forceinline__ float interp_lut8(float x,
                                             const float* __restrict__ xp,
                                             const float* __restrict__ fp) {
    float xc = fminf(fmaxf(x, xp[0]), xp[7]);
    int idx = 0;
#pragma unroll
    for (int i = 0; i < 8; ++i) idx += (xp[i] < xc) ? 1 : 0;  // count strictly-less == searchsorted left
    idx = min(max(idx, 1), 7);
    float x0 = xp[idx - 1], x1 = xp[idx];
    float f0 = fp[idx - 1], f1 = fp[idx];
    float t = (xc - x0) / (x1 - x0 + 1e-12f);
    return f0 + t * (f1 - f0);
}

__global__ __launch_bounds__(256) void PamDelayModel_kernel(
        const float* __restrict__ target,
        const float* __restrict__ buffer,
        const float* __restrict__ current,
        const float* __restrict__ tau_p,
        const float* __restrict__ tau_v,
        const float* __restrict__ dead_p,
        const float* __restrict__ dead_v,
        const int* __restrict__ wp_ptr,
        float* __restrict__ out,
        int n_elems) {
    int t = blockIdx.x * blockDim.x + threadIdx.x;
    int base = t * 4;
    if (base >= n_elems) return;

    int wp = *wp_ptr;
    float4 tp4  = *reinterpret_cast<const float4*>(target  + base);
    float4 cur4 = *reinterpret_cast<const float4*>(current + base);
    float tp[4]  = {tp4.x, tp4.y, tp4.z, tp4.w};
    float cur[4] = {cur4.x, cur4.y, cur4.z, cur4.w};

    int   idx0[4], idx1[4];
    float alpha[4], af[4];
#pragma unroll
    for (int e = 0; e < 4; ++e) {
        float L   = interp_lut8(tp[e], dead_p, dead_v);
        float tau = interp_lut8(tp[e], tau_p, tau_v);
        float D  = fminf(fmaxf(L / DT_F, 0.0f), (float)(BUFLEN - 2));
        float ri = fmodf((float)wp - D, (float)BUFLEN);
        if (ri < 0.0f) ri += (float)BUFLEN;
        int i0 = (int)floorf(ri);
        if (i0 >= BUFLEN) i0 -= BUFLEN;
        int i1 = i0 + 1;
        if (i1 >= BUFLEN) i1 -= BUFLEN;
        idx0[e] = i0;
        idx1[e] = i1;
        alpha[e] = ri - (float)i0;
        af[e] = DT_F / (tau + DT_F);
    }

    // Issue all 8 independent gathers before consuming any (MLP).
    float v0[4], v1[4];
#pragma unroll
    for (int e = 0; e < 4; ++e) {
        const float* row = buffer + (size_t)(base + e) * BUFLEN;
        v0[e] = row[idx0[e]];
        v1[e] = row[idx1[e]];
    }

    float res[4];
#pragma unroll
    for (int e = 0; e < 4; ++e) {
        // .at[:, :, write_ptr].set(target) is functional: substitute in read path
        float a0 = (idx0[e] == wp) ? tp[e] : v0[e];
        float a1 = (idx1[e] == wp) ? tp[e] : v1[e];
        float delayed = (1.0f - alpha[e]) * a0 + alpha[e] * a1;
        res[e] = (1.0f - af[e]) * cur[e] + af[e] * delayed;
    }

    *reinterpret_cast<float4*>(out + base) = make_float4(res[0], res[1], res[2], res[3]);
}

extern "C" void kernel_launch(void* const* d_in, const int* in_sizes, int n_in,
                              void* d_out, int out_size, void* d_ws, size_t ws_size,
                              hipStream_t stream) {
    const float* target  = (const float*)d_in[0];
    const float* buffer  = (const float*)d_in[1];
    const float* current = (const float*)d_in[2];
    const float* tau_p   = (const float*)d_in[3];
    const float* tau_v   = (const float*)d_in[4];
    const float* dead_p  = (const float*)d_in[5];
    const float* dead_v  = (const float*)d_in[6];
    const int*   wp_ptr  = (const int*)d_in[7];
    float* out = (float*)d_out;

    int n = out_size;  // 16384 * 16 = 262144, divisible by 4
    int block = 256;
    int grid = (n / 4 + block - 1) / block;  // 256 blocks
    PamDelayModel_kernel<<<grid, block, 0, stream>>>(
        target, buffer, current, tau_p, tau_v, dead_p, dead_v, wp_ptr, out, n);
}